// Round 15
// baseline (866.472 us; speedup 1.0000x reference)
//
#include <hip/hip_runtime.h>
#include <hip/hip_fp16.h>
#include <math.h>

#define N_NODES 50000
#define E_EDGES 800000
#define E2 (E_EDGES + N_NODES)
#define HID 128
#define HEADS 4
#define OUTC 64
#define DEPTH 4
#define NEG_SLOPE 0.2f
#define LN_EPS 1e-6f
#define NT2 3125          // 16-row tiles (50000/16 exactly)

typedef float f32x4 __attribute__((ext_vector_type(4)));
typedef float f32x2 __attribute__((ext_vector_type(2)));
typedef _Float16 half8 __attribute__((ext_vector_type(8)));

// ---------------- CSR build ----------------

__global__ void k_deg(const int* __restrict__ ei, int* __restrict__ deg) {
    int e = blockIdx.x * 256 + threadIdx.x;
    if (e >= E2) return;
    int d = (e < E_EDGES) ? ei[E_EDGES + e] : (e - E_EDGES);
    atomicAdd(&deg[d], 1);
}

__global__ void k_scan_block(const int* __restrict__ deg, int* __restrict__ partial,
                             int* __restrict__ bsum, int n) {
    __shared__ int sm[1024];
    int i = blockIdx.x * 1024 + threadIdx.x;
    int v = (i < n) ? deg[i] : 0;
    sm[threadIdx.x] = v;
    __syncthreads();
    for (int off = 1; off < 1024; off <<= 1) {
        int t = (threadIdx.x >= off) ? sm[threadIdx.x - off] : 0;
        __syncthreads();
        sm[threadIdx.x] += t;
        __syncthreads();
    }
    if (i < n) partial[i] = sm[threadIdx.x];
    if (threadIdx.x == 1023) bsum[blockIdx.x] = sm[1023];
}

__global__ void k_scan_bsum(int* __restrict__ bsum, int nb) {
    if (threadIdx.x == 0 && blockIdx.x == 0) {
        int run = 0;
        for (int b = 0; b < nb; ++b) { int v = bsum[b]; bsum[b] = run; run += v; }
    }
}

__global__ void k_scan_fix(const int* __restrict__ deg, int* __restrict__ row_ptr,
                           const int* __restrict__ bsum, int n) {
    int i = blockIdx.x * 1024 + threadIdx.x;
    if (i < n) row_ptr[i] = row_ptr[i] - deg[i] + bsum[blockIdx.x];
    if (i == 0) row_ptr[n] = E2;
}

__global__ void k_fill(const int* __restrict__ ei, const int* __restrict__ row_ptr,
                       int* __restrict__ cur, int* __restrict__ csr_src,
                       int* __restrict__ csr_dst) {
    int e = blockIdx.x * 256 + threadIdx.x;
    if (e >= E2) return;
    int s, d;
    if (e < E_EDGES) { s = ei[e]; d = ei[E_EDGES + e]; } else { s = d = e - E_EDGES; }
    int pos = atomicAdd(&cur[d], 1);
    int j = row_ptr[d] + pos;
    csr_src[j] = s;
    csr_dst[j] = d;
}

// ---------------- ws[layer][c][j]: fused attention weights: ws = W . att ----------------

__global__ void k_ws(const float* __restrict__ W_conv, const float* __restrict__ att_s,
                     const float* __restrict__ att_d, float* __restrict__ ws_all) {
    int idx = blockIdx.x * 256 + threadIdx.x;
    if (idx >= DEPTH * 1024) return;
    int j = idx & 7, c = (idx >> 3) & 127, layer = idx >> 10;
    int hh = j & 3, sd = j >> 2;
    const float* Wr = W_conv + (size_t)layer * 65536 + (size_t)c * 512 + hh * HID;
    const float* at = (sd ? att_d : att_s) + (size_t)layer * HEADS * HID + hh * HID;
    float s = 0.f;
    for (int cc = 0; cc < HID; ++cc) s += Wr[cc] * at[cc];
    ws_all[idx] = s;
}

// ---------------- repack W_conv into gemm2 B-frags: B''[k=h*128+s][n] = W[c(s), h*128+n]/4 ----
// storage perm: s = l15*8 + nt  ->  logical channel c = (s&7)*16 + (s>>3)

__global__ void k_repackB2(const float* __restrict__ W_conv, _Float16* __restrict__ Bp) {
    int idx = blockIdx.x * 256 + threadIdx.x;
    if (idx >= DEPTH * 65536) return;
    int jj    = idx & 7;
    int lane  = (idx >> 3) & 63;
    int kc    = (idx >> 9) & 15;
    int ntile = (idx >> 13) & 7;
    int layer = idx >> 16;
    int k = kc * 32 + (lane >> 4) * 8 + jj;
    int n = ntile * 16 + (lane & 15);
    int hh = k >> 7;
    int s  = k & 127;
    int c  = (s & 7) * 16 + (s >> 3);
    Bp[idx] = (_Float16)(0.25f * W_conv[(size_t)layer * 65536 + (size_t)c * 512 + hh * HID + n]);
}

// ---------------- input projection + LN -> fp8 ln table (perm layout) + layer-0 alphas ----------------

__global__ __launch_bounds__(256) void k_in_proj_ln(const float* __restrict__ x,
                                                    const float* __restrict__ W,
                                                    const float* __restrict__ bias,
                                                    const float* __restrict__ gamma,
                                                    const float* __restrict__ beta,
                                                    const float* __restrict__ ws,
                                                    float* __restrict__ h,
                                                    unsigned char* __restrict__ ln8,
                                                    float* __restrict__ as_,
                                                    float* __restrict__ ad_) {
    int tid = threadIdx.x;
    int lane = tid & 63;
    int nd = blockIdx.x * 4 + (tid >> 6);
    const float* xr = x + nd * 3;
    float x0 = xr[0], x1 = xr[1], x2 = xr[2];
    int j0 = lane, j1 = lane + 64;
    float a = bias[j0] + x0 * W[j0] + x1 * W[HID + j0] + x2 * W[2 * HID + j0];
    float b = bias[j1] + x0 * W[j1] + x1 * W[HID + j1] + x2 * W[2 * HID + j1];
    size_t base = (size_t)nd * HID;
    h[base + j0] = a;
    h[base + j1] = b;
    float s = a + b;
    for (int o = 1; o < 64; o <<= 1) s += __shfl_xor(s, o);
    float mu = s * (1.0f / 128.0f);
    float da = a - mu, db = b - mu;
    float v = da * da + db * db;
    for (int o = 1; o < 64; o <<= 1) v += __shfl_xor(v, o);
    float rstd = rsqrtf(v * (1.0f / 128.0f) + LN_EPS);
    float va = da * rstd * gamma[j0] + beta[j0];
    float vb = db * rstd * gamma[j1] + beta[j1];

    // layer-0 alphas
    float ap[8];
    for (int j = 0; j < 8; ++j)
        ap[j] = va * ws[j0 * 8 + j] + vb * ws[j1 * 8 + j];
    for (int o = 1; o < 64; o <<= 1)
        for (int j = 0; j < 8; ++j) ap[j] += __shfl_xor(ap[j], o);
    if (lane == 0) {
        for (int hh = 0; hh < 4; ++hh) {
            as_[nd * 4 + hh] = ap[hh];
            ad_[nd * 4 + hh] = ap[4 + hh];
        }
    }

    // fp8 table write (perm layout): storage s = lane*8 + t holds logical channel c = t*16 + lane
    float pv[8];
    for (int t = 0; t < 8; ++t) {
        int c = t * 16 + (lane & 15);
        float s1 = __shfl(va, c & 63);
        float s2 = __shfl(vb, c & 63);
        pv[t] = (c < 64) ? s1 : s2;
    }
    if (lane < 16) {
        int w0 = __builtin_amdgcn_cvt_pk_fp8_f32(pv[0], pv[1], 0, false);
        w0     = __builtin_amdgcn_cvt_pk_fp8_f32(pv[2], pv[3], w0, true);
        int w1 = __builtin_amdgcn_cvt_pk_fp8_f32(pv[4], pv[5], 0, false);
        w1     = __builtin_amdgcn_cvt_pk_fp8_f32(pv[6], pv[7], w1, true);
        *(int2*)(ln8 + base + lane * 8) = make_int2(w0, w1);
    }
}

// ---------------- per-edge softmax numerators ----------------

__global__ __launch_bounds__(256) void k_edge(const int* __restrict__ csr_src,
                                              const int* __restrict__ csr_dst,
                                              const float* __restrict__ as_,
                                              const float* __restrict__ ad_,
                                              float* __restrict__ p) {
    int j = blockIdx.x * 256 + threadIdx.x;
    if (j >= E2) return;
    int s = csr_src[j];
    int d = csr_dst[j];
    float4 a4 = *(const float4*)(as_ + (size_t)s * 4);
    float4 b4 = *(const float4*)(ad_ + (size_t)d * 4);
    float4 r;
    float v;
    v = a4.x + b4.x; v = (v >= 0.f) ? v : NEG_SLOPE * v; r.x = __expf(v);
    v = a4.y + b4.y; v = (v >= 0.f) ? v : NEG_SLOPE * v; r.y = __expf(v);
    v = a4.z + b4.z; v = (v >= 0.f) ? v : NEG_SLOPE * v; r.z = __expf(v);
    v = a4.w + b4.w; v = (v >= 0.f) ? v : NEG_SLOPE * v; r.w = __expf(v);
    *(float4*)(p + (size_t)j * 4) = r;
}

// ---------------- per-node aggregate of fp8 LN rows; output in MFMA A-frag layout ----------------
// agg frag layout: [tile][kc(16)][fraglane(64)][j(8)] fp16.
// This wave's lane owns channels k = h*128 + lane*2 + {0,1} (perm storage order):
//   kc = h*4 + (lane>>4), fraglane = ((lane&15)>>2)*16 + (nd&15), j0 = 2*(lane&3).

__global__ __launch_bounds__(256) void k_agg(const unsigned char* __restrict__ ln8,
                                             const float* __restrict__ p,
                                             const int* __restrict__ row_ptr,
                                             const int* __restrict__ csr_src,
                                             _Float16* __restrict__ agg) {
    __shared__ float lds[2][64][12];
    int tid = threadIdx.x;
    int lane = tid & 63;
    int wv = tid >> 6;
    int nib = wv >> 1;
    int half = wv & 1;
    int nd = blockIdx.x * 2 + nib;
    int start = row_ptr[nd], end = row_ptr[nd + 1];
    int mid = start + ((end - start + 1) >> 1);
    int s0 = half ? mid : start;
    int s1 = half ? end : mid;

    f32x2 ac0 = (f32x2)(0.f), ac1 = (f32x2)(0.f), ac2 = (f32x2)(0.f), ac3 = (f32x2)(0.f);
    float z0 = 0.f, z1 = 0.f, z2 = 0.f, z3 = 0.f;
    const unsigned char* xbase = ln8 + lane * 2;

    int e = s0;
    for (; e + 4 <= s1; e += 4) {
        int src0 = csr_src[e], src1 = csr_src[e + 1], src2 = csr_src[e + 2], src3 = csr_src[e + 3];
        float4 p0 = *(const float4*)(p + (size_t)(e + 0) * 4);
        float4 p1 = *(const float4*)(p + (size_t)(e + 1) * 4);
        float4 p2 = *(const float4*)(p + (size_t)(e + 2) * 4);
        float4 p3 = *(const float4*)(p + (size_t)(e + 3) * 4);
        unsigned short w0 = *(const unsigned short*)(xbase + (size_t)src0 * 128);
        unsigned short w1 = *(const unsigned short*)(xbase + (size_t)src1 * 128);
        unsigned short w2 = *(const unsigned short*)(xbase + (size_t)src2 * 128);
        unsigned short w3 = *(const unsigned short*)(xbase + (size_t)src3 * 128);
        f32x2 v0 = __builtin_amdgcn_cvt_pk_f32_fp8((int)w0, false);
        f32x2 v1 = __builtin_amdgcn_cvt_pk_f32_fp8((int)w1, false);
        f32x2 v2 = __builtin_amdgcn_cvt_pk_f32_fp8((int)w2, false);
        f32x2 v3 = __builtin_amdgcn_cvt_pk_f32_fp8((int)w3, false);
        ac0 += (f32x2)(p0.x) * v0 + (f32x2)(p1.x) * v1 + (f32x2)(p2.x) * v2 + (f32x2)(p3.x) * v3;
        ac1 += (f32x2)(p0.y) * v0 + (f32x2)(p1.y) * v1 + (f32x2)(p2.y) * v2 + (f32x2)(p3.y) * v3;
        ac2 += (f32x2)(p0.z) * v0 + (f32x2)(p1.z) * v1 + (f32x2)(p2.z) * v2 + (f32x2)(p3.z) * v3;
        ac3 += (f32x2)(p0.w) * v0 + (f32x2)(p1.w) * v1 + (f32x2)(p2.w) * v2 + (f32x2)(p3.w) * v3;
        z0 += (p0.x + p1.x) + (p2.x + p3.x);
        z1 += (p0.y + p1.y) + (p2.y + p3.y);
        z2 += (p0.z + p1.z) + (p2.z + p3.z);
        z3 += (p0.w + p1.w) + (p2.w + p3.w);
    }
    for (; e < s1; ++e) {
        int src0 = csr_src[e];
        float4 p0 = *(const float4*)(p + (size_t)e * 4);
        unsigned short w0 = *(const unsigned short*)(xbase + (size_t)src0 * 128);
        f32x2 v0 = __builtin_amdgcn_cvt_pk_f32_fp8((int)w0, false);
        ac0 += (f32x2)(p0.x) * v0;
        ac1 += (f32x2)(p0.y) * v0;
        ac2 += (f32x2)(p0.z) * v0;
        ac3 += (f32x2)(p0.w) * v0;
        z0 += p0.x; z1 += p0.y; z2 += p0.z; z3 += p0.w;
    }

    if (half) {
        float* L = lds[nib][lane];
        L[0] = ac0[0]; L[1] = ac0[1]; L[2] = ac1[0]; L[3] = ac1[1];
        L[4] = ac2[0]; L[5] = ac2[1]; L[6] = ac3[0]; L[7] = ac3[1];
        L[8] = z0; L[9] = z1; L[10] = z2; L[11] = z3;
    }
    __syncthreads();
    if (half) return;
    {
        const float* L = lds[nib][lane];
        ac0[0] += L[0]; ac0[1] += L[1]; ac1[0] += L[2]; ac1[1] += L[3];
        ac2[0] += L[4]; ac2[1] += L[5]; ac3[0] += L[6]; ac3[1] += L[7];
        z0 += L[8]; z1 += L[9]; z2 += L[10]; z3 += L[11];
    }
    ac0 *= (f32x2)(1.0f / z0);
    ac1 *= (f32x2)(1.0f / z1);
    ac2 *= (f32x2)(1.0f / z2);
    ac3 *= (f32x2)(1.0f / z3);

    // frag-layout packed stores (4B = 2 fp16 per head)
    int tile = nd >> 4, m = nd & 15;
    int kcb  = lane >> 4;                     // kc = h*4 + kcb
    int fraglane = ((lane & 15) >> 2) * 16 + m;
    int j0 = 2 * (lane & 3);
    union { _Float16 hx[2]; unsigned int u; } cv;
    size_t tb = (size_t)tile * 16;
    cv.hx[0] = (_Float16)ac0[0]; cv.hx[1] = (_Float16)ac0[1];
    *(unsigned int*)(agg + ((tb + 0 * 4 + kcb) * 64 + fraglane) * 8 + j0) = cv.u;
    cv.hx[0] = (_Float16)ac1[0]; cv.hx[1] = (_Float16)ac1[1];
    *(unsigned int*)(agg + ((tb + 1 * 4 + kcb) * 64 + fraglane) * 8 + j0) = cv.u;
    cv.hx[0] = (_Float16)ac2[0]; cv.hx[1] = (_Float16)ac2[1];
    *(unsigned int*)(agg + ((tb + 2 * 4 + kcb) * 64 + fraglane) * 8 + j0) = cv.u;
    cv.hx[0] = (_Float16)ac3[0]; cv.hx[1] = (_Float16)ac3[1];
    *(unsigned int*)(agg + ((tb + 3 * 4 + kcb) * 64 + fraglane) * 8 + j0) = cv.u;
}

// ---------------- gemm2: agg(frag)[N,512] x B''[512,128] -> epilogue -> h, ln8, alphas ----------------
// one wave per 16-row x 128-col tile; A loads are contiguous 1KB wave loads now.

__global__ __launch_bounds__(256) void k_gemm2(const _Float16* __restrict__ agg,
                                               const _Float16* __restrict__ Bp,
                                               const float* __restrict__ ws,
                                               const float* __restrict__ bias,
                                               const float* __restrict__ gamma,
                                               const float* __restrict__ beta,
                                               float* __restrict__ h,
                                               unsigned char* __restrict__ ln8,
                                               float* __restrict__ as_,
                                               float* __restrict__ ad_,
                                               int write_ln) {
    int tid = threadIdx.x;
    int lane = tid & 63;
    int w = tid >> 6;
    int tile = blockIdx.x * 4 + w;
    if (tile >= NT2) return;            // no barriers; h is RMW so no duplicates allowed
    int quad = lane >> 4;
    int l15  = lane & 15;

    f32x4 acc[8];
    for (int nt = 0; nt < 8; ++nt) acc[nt] = (f32x4)(0.0f);

    const _Float16* abase = agg + (size_t)tile * 8192 + lane * 8;
    for (int kc = 0; kc < 16; ++kc) {
        half8 a = *(const half8*)(abase + kc * 512);
        for (int nt = 0; nt < 8; ++nt) {
            half8 b = *(const half8*)(Bp + (((size_t)(nt * 16 + kc)) * 64 + lane) * 8);
            acc[nt] = __builtin_amdgcn_mfma_f32_16x16x32_f16(a, b, acc[nt], 0, 0, 0);
        }
    }

    int row0 = tile * 16;
    float bi[8];
    for (int nt = 0; nt < 8; ++nt) bi[nt] = bias[nt * 16 + l15];
    float ga[8], be[8], wsv[8][8];
    if (write_ln) {
        for (int nt = 0; nt < 8; ++nt) {
            int c = nt * 16 + l15;
            ga[nt] = gamma[c];
            be[nt] = beta[c];
            for (int j = 0; j < 8; ++j) wsv[nt][j] = ws[c * 8 + j];
        }
    }

    for (int r = 0; r < 4; ++r) {
        int node = row0 + quad * 4 + r;
        float* hr = h + (size_t)node * HID;
        float rv[8];
        for (int nt = 0; nt < 8; ++nt) {
            float t = acc[nt][r] + bi[nt];
            t = fmaxf(t, 0.f);
            rv[nt] = t + hr[nt * 16 + l15];
        }
        for (int nt = 0; nt < 8; ++nt) hr[nt * 16 + l15] = rv[nt];

        if (write_ln) {
            float s = 0.f;
            for (int nt = 0; nt < 8; ++nt) s += rv[nt];
            s += __shfl_xor(s, 1); s += __shfl_xor(s, 2);
            s += __shfl_xor(s, 4); s += __shfl_xor(s, 8);
            float mu = s * (1.0f / 128.0f);
            float var = 0.f;
            for (int nt = 0; nt < 8; ++nt) { float d = rv[nt] - mu; var += d * d; }
            var += __shfl_xor(var, 1); var += __shfl_xor(var, 2);
            var += __shfl_xor(var, 4); var += __shfl_xor(var, 8);
            float rstd = rsqrtf(var * (1.0f / 128.0f) + LN_EPS);
            float lnv[8];
            for (int nt = 0; nt < 8; ++nt)
                lnv[nt] = (rv[nt] - mu) * rstd * ga[nt] + be[nt];

            float ap[8];
            for (int j = 0; j < 8; ++j) {
                float t = 0.f;
                for (int nt = 0; nt < 8; ++nt) t += lnv[nt] * wsv[nt][j];
                ap[j] = t;
            }
            for (int j = 0; j < 8; ++j) {
                ap[j] += __shfl_xor(ap[j], 1); ap[j] += __shfl_xor(ap[j], 2);
                ap[j] += __shfl_xor(ap[j], 4); ap[j] += __shfl_xor(ap[j], 8);
            }
            if (l15 == 0) {
                for (int hh = 0; hh < 4; ++hh) {
                    as_[node * 4 + hh] = ap[hh];
                    ad_[node * 4 + hh] = ap[4 + hh];
                }
            }

            int w0 = __builtin_amdgcn_cvt_pk_fp8_f32(lnv[0], lnv[1], 0, false);
            w0     = __builtin_amdgcn_cvt_pk_fp8_f32(lnv[2], lnv[3], w0, true);
            int w1 = __builtin_amdgcn_cvt_pk_fp8_f32(lnv[4], lnv[5], 0, false);
            w1     = __builtin_amdgcn_cvt_pk_fp8_f32(lnv[6], lnv[7], w1, true);
            *(int2*)(ln8 + (size_t)node * 128 + l15 * 8) = make_int2(w0, w1);
        }
    }
}

// ---------------- output projection: LDS-staged W, 8 nodes/block, 2 nodes/thread ----------------

__global__ __launch_bounds__(256) void k_out_proj(const float* __restrict__ h,
                                                  const float* __restrict__ W,
                                                  const float* __restrict__ b,
                                                  float* __restrict__ out) {
    __shared__ float Ws[HID * OUTC];
    int tid = threadIdx.x;
    for (int it = 0; it < 8; ++it) {
        int idx = (tid + it * 256) * 4;
        *(float4*)&Ws[idx] = *(const float4*)(W + idx);
    }
    __syncthreads();
    int j = tid & 63;
    int sub = tid >> 6;
    int nd0 = blockIdx.x * 8 + sub * 2;
    const float* h0 = h + (size_t)nd0 * HID;
    const float* h1 = h0 + HID;
    float a0 = b[j], a1 = a0;
    #pragma unroll 8
    for (int k = 0; k < HID; ++k) {
        float w = Ws[k * OUTC + j];
        a0 += h0[k] * w;
        a1 += h1[k] * w;
    }
    out[(size_t)nd0 * OUTC + j]       = a0;
    out[(size_t)(nd0 + 1) * OUTC + j] = a1;
}

// ---------------- launch ----------------

extern "C" void kernel_launch(void* const* d_in, const int* in_sizes, int n_in,
                              void* d_out, int out_size, void* d_ws, size_t ws_size,
                              hipStream_t stream) {
    const float* x       = (const float*)d_in[0];
    const int*   ei      = (const int*)d_in[1];
    const float* W_in    = (const float*)d_in[2];
    const float* b_in    = (const float*)d_in[3];
    const float* W_conv  = (const float*)d_in[4];
    const float* att_src = (const float*)d_in[5];
    const float* att_dst = (const float*)d_in[6];
    const float* b_conv  = (const float*)d_in[7];
    const float* ln_g    = (const float*)d_in[8];
    const float* ln_b    = (const float*)d_in[9];
    const float* W_out   = (const float*)d_in[10];
    const float* b_out   = (const float*)d_in[11];
    float* out = (float*)d_out;

    char* ws = (char*)d_ws;
    size_t off = 0;
    auto alloc = [&](size_t bytes) { void* p = ws + off; off = (off + bytes + 255) & ~(size_t)255; return p; };
    float* h            = (float*)alloc((size_t)N_NODES * HID * 4);
    _Float16* agg       = (_Float16*)alloc((size_t)NT2 * 8192 * 2);   // frag layout
    unsigned char* ln8  = (unsigned char*)alloc((size_t)N_NODES * 128);
    float* as_          = (float*)alloc((size_t)N_NODES * 4 * 4);
    float* ad_          = (float*)alloc((size_t)N_NODES * 4 * 4);
    float* pedge        = (float*)alloc((size_t)E2 * HEADS * 4);
    _Float16* Bp2       = (_Float16*)alloc((size_t)DEPTH * 65536 * 2);
    float* ws_all       = (float*)alloc((size_t)DEPTH * 1024 * 4);
    int* deg    = (int*)alloc((size_t)N_NODES * 4);
    int* cur    = (int*)alloc((size_t)N_NODES * 4);
    int* row_ptr= (int*)alloc((size_t)(N_NODES + 1) * 4);
    int* csr    = (int*)alloc((size_t)E2 * 4);
    int* csrd   = (int*)alloc((size_t)E2 * 4);
    int* bsum   = (int*)alloc(256 * 4);
    (void)ws_size; (void)n_in; (void)in_sizes; (void)out_size;

    hipMemsetAsync(deg, 0, (size_t)N_NODES * 4, stream);
    hipMemsetAsync(cur, 0, (size_t)N_NODES * 4, stream);

    // CSR build
    k_deg<<<(E2 + 255) / 256, 256, 0, stream>>>(ei, deg);
    int nb = (N_NODES + 1023) / 1024;
    k_scan_block<<<nb, 1024, 0, stream>>>(deg, row_ptr, bsum, N_NODES);
    k_scan_bsum<<<1, 64, 0, stream>>>(bsum, nb);
    k_scan_fix<<<nb, 1024, 0, stream>>>(deg, row_ptr, bsum, N_NODES);
    k_fill<<<(E2 + 255) / 256, 256, 0, stream>>>(ei, row_ptr, cur, csr, csrd);

    // weight preprocessing (per call; graph-safe)
    k_ws<<<(DEPTH * 1024 + 255) / 256, 256, 0, stream>>>(W_conv, att_src, att_dst, ws_all);
    k_repackB2<<<(DEPTH * 65536 + 255) / 256, 256, 0, stream>>>(W_conv, Bp2);

    // input projection + first LN (fp8 table + layer-0 alphas)
    k_in_proj_ln<<<N_NODES / 4, 256, 0, stream>>>(x, W_in, b_in, ln_g, ln_b, ws_all,
                                                  h, ln8, as_, ad_);

    // layers
    for (int i = 0; i < DEPTH; ++i) {
        const float* bcp = b_conv + (size_t)i * HID;
        int write_ln = (i + 1 < DEPTH) ? 1 : 0;
        int nl = (i + 1 < DEPTH) ? i + 1 : i;
        const float* gp = ln_g + (size_t)nl * HID;
        const float* bp = ln_b + (size_t)nl * HID;
        const float* wsp = ws_all + (size_t)nl * 1024;

        k_edge<<<(E2 + 255) / 256, 256, 0, stream>>>(csr, csrd, as_, ad_, pedge);
        k_agg<<<N_NODES / 2, 256, 0, stream>>>(ln8, pedge, row_ptr, csr, agg);
        k_gemm2<<<(NT2 + 3) / 4, 256, 0, stream>>>(agg, Bp2 + (size_t)i * 65536, wsp,
                                                   bcp, gp, bp, h, ln8, as_, ad_, write_ln);
    }

    k_out_proj<<<N_NODES / 8, 256, 0, stream>>>(h, W_out, b_out, out);
}

// Round 16
// 651.585 us; speedup vs baseline: 1.3298x; 1.3298x over previous
//
#include <hip/hip_runtime.h>
#include <hip/hip_fp16.h>
#include <math.h>

#define N_NODES 50000
#define E_EDGES 800000
#define E2 (E_EDGES + N_NODES)
#define HID 128
#define HEADS 4
#define OUTC 64
#define DEPTH 4
#define NEG_SLOPE 0.2f
#define LN_EPS 1e-6f
#define NT2 3125          // 16-row tiles (50000/16 exactly)

typedef float f32x4 __attribute__((ext_vector_type(4)));
typedef float f32x2 __attribute__((ext_vector_type(2)));
typedef _Float16 half8 __attribute__((ext_vector_type(8)));

// ---------------- CSR build ----------------

__global__ void k_deg(const int* __restrict__ ei, int* __restrict__ deg) {
    int e = blockIdx.x * 256 + threadIdx.x;
    if (e >= E2) return;
    int d = (e < E_EDGES) ? ei[E_EDGES + e] : (e - E_EDGES);
    atomicAdd(&deg[d], 1);
}

__global__ void k_scan_block(const int* __restrict__ deg, int* __restrict__ partial,
                             int* __restrict__ bsum, int n) {
    __shared__ int sm[1024];
    int i = blockIdx.x * 1024 + threadIdx.x;
    int v = (i < n) ? deg[i] : 0;
    sm[threadIdx.x] = v;
    __syncthreads();
    for (int off = 1; off < 1024; off <<= 1) {
        int t = (threadIdx.x >= off) ? sm[threadIdx.x - off] : 0;
        __syncthreads();
        sm[threadIdx.x] += t;
        __syncthreads();
    }
    if (i < n) partial[i] = sm[threadIdx.x];
    if (threadIdx.x == 1023) bsum[blockIdx.x] = sm[1023];
}

__global__ void k_scan_bsum(int* __restrict__ bsum, int nb) {
    if (threadIdx.x == 0 && blockIdx.x == 0) {
        int run = 0;
        for (int b = 0; b < nb; ++b) { int v = bsum[b]; bsum[b] = run; run += v; }
    }
}

__global__ void k_scan_fix(const int* __restrict__ deg, int* __restrict__ row_ptr,
                           const int* __restrict__ bsum, int n) {
    int i = blockIdx.x * 1024 + threadIdx.x;
    if (i < n) row_ptr[i] = row_ptr[i] - deg[i] + bsum[blockIdx.x];
    if (i == 0) row_ptr[n] = E2;
}

__global__ void k_fill(const int* __restrict__ ei, const int* __restrict__ row_ptr,
                       int* __restrict__ cur, int* __restrict__ csr_src,
                       int* __restrict__ csr_dst) {
    int e = blockIdx.x * 256 + threadIdx.x;
    if (e >= E2) return;
    int s, d;
    if (e < E_EDGES) { s = ei[e]; d = ei[E_EDGES + e]; } else { s = d = e - E_EDGES; }
    int pos = atomicAdd(&cur[d], 1);
    int j = row_ptr[d] + pos;
    csr_src[j] = s;
    csr_dst[j] = d;
}

// ---------------- ws[layer][c][j]: fused attention weights: ws = W . att ----------------

__global__ void k_ws(const float* __restrict__ W_conv, const float* __restrict__ att_s,
                     const float* __restrict__ att_d, float* __restrict__ ws_all) {
    int idx = blockIdx.x * 256 + threadIdx.x;
    if (idx >= DEPTH * 1024) return;
    int j = idx & 7, c = (idx >> 3) & 127, layer = idx >> 10;
    int hh = j & 3, sd = j >> 2;
    const float* Wr = W_conv + (size_t)layer * 65536 + (size_t)c * 512 + hh * HID;
    const float* at = (sd ? att_d : att_s) + (size_t)layer * HEADS * HID + hh * HID;
    float s = 0.f;
    for (int cc = 0; cc < HID; ++cc) s += Wr[cc] * at[cc];
    ws_all[idx] = s;
}

// ---------------- repack W_conv into gemm2 B-frags: B''[k=h*128+s][n] = W[c(s), h*128+n]/4 ----
// storage perm: s = l15*8 + nt  ->  logical channel c = (s&7)*16 + (s>>3)

__global__ void k_repackB2(const float* __restrict__ W_conv, _Float16* __restrict__ Bp) {
    int idx = blockIdx.x * 256 + threadIdx.x;
    if (idx >= DEPTH * 65536) return;
    int jj    = idx & 7;
    int lane  = (idx >> 3) & 63;
    int kc    = (idx >> 9) & 15;
    int ntile = (idx >> 13) & 7;
    int layer = idx >> 16;
    int k = kc * 32 + (lane >> 4) * 8 + jj;
    int n = ntile * 16 + (lane & 15);
    int hh = k >> 7;
    int s  = k & 127;
    int c  = (s & 7) * 16 + (s >> 3);
    Bp[idx] = (_Float16)(0.25f * W_conv[(size_t)layer * 65536 + (size_t)c * 512 + hh * HID + n]);
}

// ---------------- input projection + LN -> fp8 ln table (perm layout) + layer-0 alphas ----------------

__global__ __launch_bounds__(256) void k_in_proj_ln(const float* __restrict__ x,
                                                    const float* __restrict__ W,
                                                    const float* __restrict__ bias,
                                                    const float* __restrict__ gamma,
                                                    const float* __restrict__ beta,
                                                    const float* __restrict__ ws,
                                                    float* __restrict__ h,
                                                    unsigned char* __restrict__ ln8,
                                                    float* __restrict__ as_,
                                                    float* __restrict__ ad_) {
    int tid = threadIdx.x;
    int lane = tid & 63;
    int nd = blockIdx.x * 4 + (tid >> 6);
    const float* xr = x + nd * 3;
    float x0 = xr[0], x1 = xr[1], x2 = xr[2];
    int j0 = lane, j1 = lane + 64;
    float a = bias[j0] + x0 * W[j0] + x1 * W[HID + j0] + x2 * W[2 * HID + j0];
    float b = bias[j1] + x0 * W[j1] + x1 * W[HID + j1] + x2 * W[2 * HID + j1];
    size_t base = (size_t)nd * HID;
    h[base + j0] = a;
    h[base + j1] = b;
    float s = a + b;
    for (int o = 1; o < 64; o <<= 1) s += __shfl_xor(s, o);
    float mu = s * (1.0f / 128.0f);
    float da = a - mu, db = b - mu;
    float v = da * da + db * db;
    for (int o = 1; o < 64; o <<= 1) v += __shfl_xor(v, o);
    float rstd = rsqrtf(v * (1.0f / 128.0f) + LN_EPS);
    float va = da * rstd * gamma[j0] + beta[j0];
    float vb = db * rstd * gamma[j1] + beta[j1];

    // layer-0 alphas
    float ap[8];
    for (int j = 0; j < 8; ++j)
        ap[j] = va * ws[j0 * 8 + j] + vb * ws[j1 * 8 + j];
    for (int o = 1; o < 64; o <<= 1)
        for (int j = 0; j < 8; ++j) ap[j] += __shfl_xor(ap[j], o);
    if (lane == 0) {
        for (int hh = 0; hh < 4; ++hh) {
            as_[nd * 4 + hh] = ap[hh];
            ad_[nd * 4 + hh] = ap[4 + hh];
        }
    }

    // fp8 table write (perm layout): storage s = lane*8 + t holds logical channel c = t*16 + lane
    float pv[8];
    for (int t = 0; t < 8; ++t) {
        int c = t * 16 + (lane & 15);
        float s1 = __shfl(va, c & 63);
        float s2 = __shfl(vb, c & 63);
        pv[t] = (c < 64) ? s1 : s2;
    }
    if (lane < 16) {
        int w0 = __builtin_amdgcn_cvt_pk_fp8_f32(pv[0], pv[1], 0, false);
        w0     = __builtin_amdgcn_cvt_pk_fp8_f32(pv[2], pv[3], w0, true);
        int w1 = __builtin_amdgcn_cvt_pk_fp8_f32(pv[4], pv[5], 0, false);
        w1     = __builtin_amdgcn_cvt_pk_fp8_f32(pv[6], pv[7], w1, true);
        *(int2*)(ln8 + base + lane * 8) = make_int2(w0, w1);
    }
}

// ---------------- per-edge softmax numerators ----------------

__global__ __launch_bounds__(256) void k_edge(const int* __restrict__ csr_src,
                                              const int* __restrict__ csr_dst,
                                              const float* __restrict__ as_,
                                              const float* __restrict__ ad_,
                                              float* __restrict__ p) {
    int j = blockIdx.x * 256 + threadIdx.x;
    if (j >= E2) return;
    int s = csr_src[j];
    int d = csr_dst[j];
    float4 a4 = *(const float4*)(as_ + (size_t)s * 4);
    float4 b4 = *(const float4*)(ad_ + (size_t)d * 4);
    float4 r;
    float v;
    v = a4.x + b4.x; v = (v >= 0.f) ? v : NEG_SLOPE * v; r.x = __expf(v);
    v = a4.y + b4.y; v = (v >= 0.f) ? v : NEG_SLOPE * v; r.y = __expf(v);
    v = a4.z + b4.z; v = (v >= 0.f) ? v : NEG_SLOPE * v; r.z = __expf(v);
    v = a4.w + b4.w; v = (v >= 0.f) ? v : NEG_SLOPE * v; r.w = __expf(v);
    *(float4*)(p + (size_t)j * 4) = r;
}

// ---------------- per-node aggregate of fp8 LN rows; 1 wave per node; A-frag output ----------------
// agg frag layout: [tile][kc(16)][fraglane(64)][j(8)] fp16.
// Lane owns channels k = h*128 + lane*2 + {0,1}:
//   kc = h*4 + (lane>>4), fraglane = ((lane&15)>>2)*16 + (nd&15), j0 = 2*(lane&3).

__global__ __launch_bounds__(256) void k_agg(const unsigned char* __restrict__ ln8,
                                             const float* __restrict__ p,
                                             const int* __restrict__ row_ptr,
                                             const int* __restrict__ csr_src,
                                             _Float16* __restrict__ agg) {
    int tid = threadIdx.x;
    int lane = tid & 63;
    int nd = blockIdx.x * 4 + (tid >> 6);
    int e = row_ptr[nd], end = row_ptr[nd + 1];

    f32x2 ac0 = (f32x2)(0.f), ac1 = (f32x2)(0.f), ac2 = (f32x2)(0.f), ac3 = (f32x2)(0.f);
    float z0 = 0.f, z1 = 0.f, z2 = 0.f, z3 = 0.f;
    const unsigned char* xbase = ln8 + lane * 2;

    for (; e + 4 <= end; e += 4) {
        int src0 = csr_src[e], src1 = csr_src[e + 1], src2 = csr_src[e + 2], src3 = csr_src[e + 3];
        float4 p0 = *(const float4*)(p + (size_t)(e + 0) * 4);
        float4 p1 = *(const float4*)(p + (size_t)(e + 1) * 4);
        float4 p2 = *(const float4*)(p + (size_t)(e + 2) * 4);
        float4 p3 = *(const float4*)(p + (size_t)(e + 3) * 4);
        unsigned short w0 = *(const unsigned short*)(xbase + (size_t)src0 * 128);
        unsigned short w1 = *(const unsigned short*)(xbase + (size_t)src1 * 128);
        unsigned short w2 = *(const unsigned short*)(xbase + (size_t)src2 * 128);
        unsigned short w3 = *(const unsigned short*)(xbase + (size_t)src3 * 128);
        f32x2 v0 = __builtin_amdgcn_cvt_pk_f32_fp8((int)w0, false);
        f32x2 v1 = __builtin_amdgcn_cvt_pk_f32_fp8((int)w1, false);
        f32x2 v2 = __builtin_amdgcn_cvt_pk_f32_fp8((int)w2, false);
        f32x2 v3 = __builtin_amdgcn_cvt_pk_f32_fp8((int)w3, false);
        ac0 += (f32x2)(p0.x) * v0 + (f32x2)(p1.x) * v1 + (f32x2)(p2.x) * v2 + (f32x2)(p3.x) * v3;
        ac1 += (f32x2)(p0.y) * v0 + (f32x2)(p1.y) * v1 + (f32x2)(p2.y) * v2 + (f32x2)(p3.y) * v3;
        ac2 += (f32x2)(p0.z) * v0 + (f32x2)(p1.z) * v1 + (f32x2)(p2.z) * v2 + (f32x2)(p3.z) * v3;
        ac3 += (f32x2)(p0.w) * v0 + (f32x2)(p1.w) * v1 + (f32x2)(p2.w) * v2 + (f32x2)(p3.w) * v3;
        z0 += (p0.x + p1.x) + (p2.x + p3.x);
        z1 += (p0.y + p1.y) + (p2.y + p3.y);
        z2 += (p0.z + p1.z) + (p2.z + p3.z);
        z3 += (p0.w + p1.w) + (p2.w + p3.w);
    }
    for (; e < end; ++e) {
        int src0 = csr_src[e];
        float4 p0 = *(const float4*)(p + (size_t)e * 4);
        unsigned short w0 = *(const unsigned short*)(xbase + (size_t)src0 * 128);
        f32x2 v0 = __builtin_amdgcn_cvt_pk_f32_fp8((int)w0, false);
        ac0 += (f32x2)(p0.x) * v0;
        ac1 += (f32x2)(p0.y) * v0;
        ac2 += (f32x2)(p0.z) * v0;
        ac3 += (f32x2)(p0.w) * v0;
        z0 += p0.x; z1 += p0.y; z2 += p0.z; z3 += p0.w;
    }

    ac0 *= (f32x2)(1.0f / z0);
    ac1 *= (f32x2)(1.0f / z1);
    ac2 *= (f32x2)(1.0f / z2);
    ac3 *= (f32x2)(1.0f / z3);

    // frag-layout packed stores (4B = 2 fp16 per head)
    int tile = nd >> 4, m = nd & 15;
    int kcb  = lane >> 4;                     // kc = h*4 + kcb
    int fraglane = ((lane & 15) >> 2) * 16 + m;
    int j0 = 2 * (lane & 3);
    union { _Float16 hx[2]; unsigned int u; } cv;
    size_t tb = (size_t)tile * 16;
    cv.hx[0] = (_Float16)ac0[0]; cv.hx[1] = (_Float16)ac0[1];
    *(unsigned int*)(agg + ((tb + 0 * 4 + kcb) * 64 + fraglane) * 8 + j0) = cv.u;
    cv.hx[0] = (_Float16)ac1[0]; cv.hx[1] = (_Float16)ac1[1];
    *(unsigned int*)(agg + ((tb + 1 * 4 + kcb) * 64 + fraglane) * 8 + j0) = cv.u;
    cv.hx[0] = (_Float16)ac2[0]; cv.hx[1] = (_Float16)ac2[1];
    *(unsigned int*)(agg + ((tb + 2 * 4 + kcb) * 64 + fraglane) * 8 + j0) = cv.u;
    cv.hx[0] = (_Float16)ac3[0]; cv.hx[1] = (_Float16)ac3[1];
    *(unsigned int*)(agg + ((tb + 3 * 4 + kcb) * 64 + fraglane) * 8 + j0) = cv.u;
}

// ---------------- gemm2: agg(frag) x B''(LDS-staged) -> epilogue -> h, ln8, alphas ----------------
// 4 waves/block, one 16-row tile each; per-kc 8KB B slice staged in LDS and shared.

__global__ __launch_bounds__(256) void k_gemm2(const _Float16* __restrict__ agg,
                                               const _Float16* __restrict__ Bp,
                                               const float* __restrict__ ws,
                                               const float* __restrict__ bias,
                                               const float* __restrict__ gamma,
                                               const float* __restrict__ beta,
                                               float* __restrict__ h,
                                               unsigned char* __restrict__ ln8,
                                               float* __restrict__ as_,
                                               float* __restrict__ ad_,
                                               int write_ln) {
    __shared__ _Float16 Bs[4096];       // 8 KB: [nt(8)][lane(64)][j(8)]
    int tid = threadIdx.x;
    int lane = tid & 63;
    int w = tid >> 6;
    int tile = blockIdx.x * 4 + w;
    int valid = (tile < NT2);
    if (!valid) tile = 0;               // stay for barriers; all global writes guarded
    int quad = lane >> 4;
    int l15  = lane & 15;

    // staging indices: thread covers 16 fp16 (32 B) of the 8 KB slice
    int ntS  = tid >> 5;
    int remS = (tid & 31) * 16;

    f32x4 acc[8];
    for (int nt = 0; nt < 8; ++nt) acc[nt] = (f32x4)(0.0f);

    const _Float16* abase = agg + (size_t)tile * 8192 + lane * 8;
    for (int kc = 0; kc < 16; ++kc) {
        half8 a = *(const half8*)(abase + kc * 512);          // global, independent of LDS
        const _Float16* src = Bp + ((size_t)(ntS * 16 + kc)) * 512 + remS;
        __syncthreads();                                      // prior kc's reads done
        *(half8*)(Bs + tid * 16)     = *(const half8*)(src);
        *(half8*)(Bs + tid * 16 + 8) = *(const half8*)(src + 8);
        __syncthreads();                                      // slice visible
        for (int nt = 0; nt < 8; ++nt) {
            half8 b = *(const half8*)(Bs + nt * 512 + lane * 8);
            acc[nt] = __builtin_amdgcn_mfma_f32_16x16x32_f16(a, b, acc[nt], 0, 0, 0);
        }
    }

    if (!valid) return;                 // no barriers below

    int row0 = tile * 16;
    float bi[8];
    for (int nt = 0; nt < 8; ++nt) bi[nt] = bias[nt * 16 + l15];
    float ga[8], be[8], wsv[8][8];
    if (write_ln) {
        for (int nt = 0; nt < 8; ++nt) {
            int c = nt * 16 + l15;
            ga[nt] = gamma[c];
            be[nt] = beta[c];
            for (int j = 0; j < 8; ++j) wsv[nt][j] = ws[c * 8 + j];
        }
    }

    for (int r = 0; r < 4; ++r) {
        int node = row0 + quad * 4 + r;
        float* hr = h + (size_t)node * HID;
        float rv[8];
        for (int nt = 0; nt < 8; ++nt) {
            float t = acc[nt][r] + bi[nt];
            t = fmaxf(t, 0.f);
            rv[nt] = t + hr[nt * 16 + l15];
        }
        for (int nt = 0; nt < 8; ++nt) hr[nt * 16 + l15] = rv[nt];

        if (write_ln) {
            float s = 0.f;
            for (int nt = 0; nt < 8; ++nt) s += rv[nt];
            s += __shfl_xor(s, 1); s += __shfl_xor(s, 2);
            s += __shfl_xor(s, 4); s += __shfl_xor(s, 8);
            float mu = s * (1.0f / 128.0f);
            float var = 0.f;
            for (int nt = 0; nt < 8; ++nt) { float d = rv[nt] - mu; var += d * d; }
            var += __shfl_xor(var, 1); var += __shfl_xor(var, 2);
            var += __shfl_xor(var, 4); var += __shfl_xor(var, 8);
            float rstd = rsqrtf(var * (1.0f / 128.0f) + LN_EPS);
            float lnv[8];
            for (int nt = 0; nt < 8; ++nt)
                lnv[nt] = (rv[nt] - mu) * rstd * ga[nt] + be[nt];

            float ap[8];
            for (int j = 0; j < 8; ++j) {
                float t = 0.f;
                for (int nt = 0; nt < 8; ++nt) t += lnv[nt] * wsv[nt][j];
                ap[j] = t;
            }
            for (int j = 0; j < 8; ++j) {
                ap[j] += __shfl_xor(ap[j], 1); ap[j] += __shfl_xor(ap[j], 2);
                ap[j] += __shfl_xor(ap[j], 4); ap[j] += __shfl_xor(ap[j], 8);
            }
            if (l15 == 0) {
                for (int hh = 0; hh < 4; ++hh) {
                    as_[node * 4 + hh] = ap[hh];
                    ad_[node * 4 + hh] = ap[4 + hh];
                }
            }

            int w0 = __builtin_amdgcn_cvt_pk_fp8_f32(lnv[0], lnv[1], 0, false);
            w0     = __builtin_amdgcn_cvt_pk_fp8_f32(lnv[2], lnv[3], w0, true);
            int w1 = __builtin_amdgcn_cvt_pk_fp8_f32(lnv[4], lnv[5], 0, false);
            w1     = __builtin_amdgcn_cvt_pk_fp8_f32(lnv[6], lnv[7], w1, true);
            *(int2*)(ln8 + (size_t)node * 128 + l15 * 8) = make_int2(w0, w1);
        }
    }
}

// ---------------- output projection: LDS-staged W, 8 nodes/block, 2 nodes/thread ----------------

__global__ __launch_bounds__(256) void k_out_proj(const float* __restrict__ h,
                                                  const float* __restrict__ W,
                                                  const float* __restrict__ b,
                                                  float* __restrict__ out) {
    __shared__ float Ws[HID * OUTC];
    int tid = threadIdx.x;
    for (int it = 0; it < 8; ++it) {
        int idx = (tid + it * 256) * 4;
        *(float4*)&Ws[idx] = *(const float4*)(W + idx);
    }
    __syncthreads();
    int j = tid & 63;
    int sub = tid >> 6;
    int nd0 = blockIdx.x * 8 + sub * 2;
    const float* h0 = h + (size_t)nd0 * HID;
    const float* h1 = h0 + HID;
    float a0 = b[j], a1 = a0;
    #pragma unroll 8
    for (int k = 0; k < HID; ++k) {
        float w = Ws[k * OUTC + j];
        a0 += h0[k] * w;
        a1 += h1[k] * w;
    }
    out[(size_t)nd0 * OUTC + j]       = a0;
    out[(size_t)(nd0 + 1) * OUTC + j] = a1;
}

// ---------------- launch ----------------

extern "C" void kernel_launch(void* const* d_in, const int* in_sizes, int n_in,
                              void* d_out, int out_size, void* d_ws, size_t ws_size,
                              hipStream_t stream) {
    const float* x       = (const float*)d_in[0];
    const int*   ei      = (const int*)d_in[1];
    const float* W_in    = (const float*)d_in[2];
    const float* b_in    = (const float*)d_in[3];
    const float* W_conv  = (const float*)d_in[4];
    const float* att_src = (const float*)d_in[5];
    const float* att_dst = (const float*)d_in[6];
    const float* b_conv  = (const float*)d_in[7];
    const float* ln_g    = (const float*)d_in[8];
    const float* ln_b    = (const float*)d_in[9];
    const float* W_out   = (const float*)d_in[10];
    const float* b_out   = (const float*)d_in[11];
    float* out = (float*)d_out;

    char* ws = (char*)d_ws;
    size_t off = 0;
    auto alloc = [&](size_t bytes) { void* p = ws + off; off = (off + bytes + 255) & ~(size_t)255; return p; };
    float* h            = (float*)alloc((size_t)N_NODES * HID * 4);
    _Float16* agg       = (_Float16*)alloc((size_t)NT2 * 8192 * 2);   // frag layout
    unsigned char* ln8  = (unsigned char*)alloc((size_t)N_NODES * 128);
    float* as_          = (float*)alloc((size_t)N_NODES * 4 * 4);
    float* ad_          = (float*)alloc((size_t)N_NODES * 4 * 4);
    float* pedge        = (float*)alloc((size_t)E2 * HEADS * 4);
    _Float16* Bp2       = (_Float16*)alloc((size_t)DEPTH * 65536 * 2);
    float* ws_all       = (float*)alloc((size_t)DEPTH * 1024 * 4);
    int* deg    = (int*)alloc((size_t)N_NODES * 4);
    int* cur    = (int*)alloc((size_t)N_NODES * 4);
    int* row_ptr= (int*)alloc((size_t)(N_NODES + 1) * 4);
    int* csr    = (int*)alloc((size_t)E2 * 4);
    int* csrd   = (int*)alloc((size_t)E2 * 4);
    int* bsum   = (int*)alloc(256 * 4);
    (void)ws_size; (void)n_in; (void)in_sizes; (void)out_size;

    hipMemsetAsync(deg, 0, (size_t)N_NODES * 4, stream);
    hipMemsetAsync(cur, 0, (size_t)N_NODES * 4, stream);

    // CSR build
    k_deg<<<(E2 + 255) / 256, 256, 0, stream>>>(ei, deg);
    int nb = (N_NODES + 1023) / 1024;
    k_scan_block<<<nb, 1024, 0, stream>>>(deg, row_ptr, bsum, N_NODES);
    k_scan_bsum<<<1, 64, 0, stream>>>(bsum, nb);
    k_scan_fix<<<nb, 1024, 0, stream>>>(deg, row_ptr, bsum, N_NODES);
    k_fill<<<(E2 + 255) / 256, 256, 0, stream>>>(ei, row_ptr, cur, csr, csrd);

    // weight preprocessing (per call; graph-safe)
    k_ws<<<(DEPTH * 1024 + 255) / 256, 256, 0, stream>>>(W_conv, att_src, att_dst, ws_all);
    k_repackB2<<<(DEPTH * 65536 + 255) / 256, 256, 0, stream>>>(W_conv, Bp2);

    // input projection + first LN (fp8 table + layer-0 alphas)
    k_in_proj_ln<<<N_NODES / 4, 256, 0, stream>>>(x, W_in, b_in, ln_g, ln_b, ws_all,
                                                  h, ln8, as_, ad_);

    // layers
    for (int i = 0; i < DEPTH; ++i) {
        const float* bcp = b_conv + (size_t)i * HID;
        int write_ln = (i + 1 < DEPTH) ? 1 : 0;
        int nl = (i + 1 < DEPTH) ? i + 1 : i;
        const float* gp = ln_g + (size_t)nl * HID;
        const float* bp = ln_b + (size_t)nl * HID;
        const float* wsp = ws_all + (size_t)nl * 1024;

        k_edge<<<(E2 + 255) / 256, 256, 0, stream>>>(csr, csrd, as_, ad_, pedge);
        k_agg<<<N_NODES / 4, 256, 0, stream>>>(ln8, pedge, row_ptr, csr, agg);
        k_gemm2<<<(NT2 + 3) / 4, 256, 0, stream>>>(agg, Bp2 + (size_t)i * 65536, wsp,
                                                   bcp, gp, bp, h, ln8, as_, ad_, write_ln);
    }

    k_out_proj<<<N_NODES / 8, 256, 0, stream>>>(h, W_out, b_out, out);
}

// Round 17
// 649.770 us; speedup vs baseline: 1.3335x; 1.0028x over previous
//
#include <hip/hip_runtime.h>
#include <hip/hip_fp16.h>
#include <math.h>

#define N_NODES 50000
#define E_EDGES 800000
#define E2 (E_EDGES + N_NODES)
#define HID 128
#define HEADS 4
#define OUTC 64
#define DEPTH 4
#define NEG_SLOPE 0.2f
#define LN_EPS 1e-6f
#define NT2 3125          // 16-row tiles (50000/16 exactly)

typedef float f32x4 __attribute__((ext_vector_type(4)));
typedef float f32x2 __attribute__((ext_vector_type(2)));
typedef _Float16 half8 __attribute__((ext_vector_type(8)));

// ---------------- CSR build ----------------

__global__ void k_deg(const int* __restrict__ ei, int* __restrict__ deg) {
    int e = blockIdx.x * 256 + threadIdx.x;
    if (e >= E2) return;
    int d = (e < E_EDGES) ? ei[E_EDGES + e] : (e - E_EDGES);
    atomicAdd(&deg[d], 1);
}

__global__ void k_scan_block(const int* __restrict__ deg, int* __restrict__ partial,
                             int* __restrict__ bsum, int n) {
    __shared__ int sm[1024];
    int i = blockIdx.x * 1024 + threadIdx.x;
    int v = (i < n) ? deg[i] : 0;
    sm[threadIdx.x] = v;
    __syncthreads();
    for (int off = 1; off < 1024; off <<= 1) {
        int t = (threadIdx.x >= off) ? sm[threadIdx.x - off] : 0;
        __syncthreads();
        sm[threadIdx.x] += t;
        __syncthreads();
    }
    if (i < n) partial[i] = sm[threadIdx.x];
    if (threadIdx.x == 1023) bsum[blockIdx.x] = sm[1023];
}

__global__ void k_scan_bsum(int* __restrict__ bsum, int nb) {
    if (threadIdx.x == 0 && blockIdx.x == 0) {
        int run = 0;
        for (int b = 0; b < nb; ++b) { int v = bsum[b]; bsum[b] = run; run += v; }
    }
}

__global__ void k_scan_fix(const int* __restrict__ deg, int* __restrict__ row_ptr,
                           const int* __restrict__ bsum, int n) {
    int i = blockIdx.x * 1024 + threadIdx.x;
    if (i < n) row_ptr[i] = row_ptr[i] - deg[i] + bsum[blockIdx.x];
    if (i == 0) row_ptr[n] = E2;
}

__global__ void k_fill(const int* __restrict__ ei, const int* __restrict__ row_ptr,
                       int* __restrict__ cur, int* __restrict__ csr_src,
                       int* __restrict__ csr_dst) {
    int e = blockIdx.x * 256 + threadIdx.x;
    if (e >= E2) return;
    int s, d;
    if (e < E_EDGES) { s = ei[e]; d = ei[E_EDGES + e]; } else { s = d = e - E_EDGES; }
    int pos = atomicAdd(&cur[d], 1);
    int j = row_ptr[d] + pos;
    csr_src[j] = s;
    csr_dst[j] = d;
}

// ---------------- ws[layer][c][j]: fused attention weights: ws = W . att ----------------

__global__ void k_ws(const float* __restrict__ W_conv, const float* __restrict__ att_s,
                     const float* __restrict__ att_d, float* __restrict__ ws_all) {
    int idx = blockIdx.x * 256 + threadIdx.x;
    if (idx >= DEPTH * 1024) return;
    int j = idx & 7, c = (idx >> 3) & 127, layer = idx >> 10;
    int hh = j & 3, sd = j >> 2;
    const float* Wr = W_conv + (size_t)layer * 65536 + (size_t)c * 512 + hh * HID;
    const float* at = (sd ? att_d : att_s) + (size_t)layer * HEADS * HID + hh * HID;
    float s = 0.f;
    for (int cc = 0; cc < HID; ++cc) s += Wr[cc] * at[cc];
    ws_all[idx] = s;
}

// ---------------- repack W_conv into gemm2 B-frags: B''[k=h*128+s][n] = W[c(s), h*128+n]/4 ----
// storage perm: s = l15*8 + nt  ->  logical channel c = (s&7)*16 + (s>>3)

__global__ void k_repackB2(const float* __restrict__ W_conv, _Float16* __restrict__ Bp) {
    int idx = blockIdx.x * 256 + threadIdx.x;
    if (idx >= DEPTH * 65536) return;
    int jj    = idx & 7;
    int lane  = (idx >> 3) & 63;
    int kc    = (idx >> 9) & 15;
    int ntile = (idx >> 13) & 7;
    int layer = idx >> 16;
    int k = kc * 32 + (lane >> 4) * 8 + jj;
    int n = ntile * 16 + (lane & 15);
    int hh = k >> 7;
    int s  = k & 127;
    int c  = (s & 7) * 16 + (s >> 3);
    Bp[idx] = (_Float16)(0.25f * W_conv[(size_t)layer * 65536 + (size_t)c * 512 + hh * HID + n]);
}

// ---------------- input projection + LN -> fp8 ln table (perm layout) + layer-0 alphas ----------------

__global__ __launch_bounds__(256) void k_in_proj_ln(const float* __restrict__ x,
                                                    const float* __restrict__ W,
                                                    const float* __restrict__ bias,
                                                    const float* __restrict__ gamma,
                                                    const float* __restrict__ beta,
                                                    const float* __restrict__ ws,
                                                    float* __restrict__ h,
                                                    unsigned char* __restrict__ ln8,
                                                    float* __restrict__ as_,
                                                    float* __restrict__ ad_) {
    int tid = threadIdx.x;
    int lane = tid & 63;
    int nd = blockIdx.x * 4 + (tid >> 6);
    const float* xr = x + nd * 3;
    float x0 = xr[0], x1 = xr[1], x2 = xr[2];
    int j0 = lane, j1 = lane + 64;
    float a = bias[j0] + x0 * W[j0] + x1 * W[HID + j0] + x2 * W[2 * HID + j0];
    float b = bias[j1] + x0 * W[j1] + x1 * W[HID + j1] + x2 * W[2 * HID + j1];
    size_t base = (size_t)nd * HID;
    h[base + j0] = a;
    h[base + j1] = b;
    float s = a + b;
    for (int o = 1; o < 64; o <<= 1) s += __shfl_xor(s, o);
    float mu = s * (1.0f / 128.0f);
    float da = a - mu, db = b - mu;
    float v = da * da + db * db;
    for (int o = 1; o < 64; o <<= 1) v += __shfl_xor(v, o);
    float rstd = rsqrtf(v * (1.0f / 128.0f) + LN_EPS);
    float va = da * rstd * gamma[j0] + beta[j0];
    float vb = db * rstd * gamma[j1] + beta[j1];

    // layer-0 alphas
    float ap[8];
    for (int j = 0; j < 8; ++j)
        ap[j] = va * ws[j0 * 8 + j] + vb * ws[j1 * 8 + j];
    for (int o = 1; o < 64; o <<= 1)
        for (int j = 0; j < 8; ++j) ap[j] += __shfl_xor(ap[j], o);
    if (lane == 0) {
        for (int hh = 0; hh < 4; ++hh) {
            as_[nd * 4 + hh] = ap[hh];
            ad_[nd * 4 + hh] = ap[4 + hh];
        }
    }

    // fp8 table write (perm layout): storage s = lane*8 + t holds logical channel c = t*16 + lane
    float pv[8];
    for (int t = 0; t < 8; ++t) {
        int c = t * 16 + (lane & 15);
        float s1 = __shfl(va, c & 63);
        float s2 = __shfl(vb, c & 63);
        pv[t] = (c < 64) ? s1 : s2;
    }
    if (lane < 16) {
        int w0 = __builtin_amdgcn_cvt_pk_fp8_f32(pv[0], pv[1], 0, false);
        w0     = __builtin_amdgcn_cvt_pk_fp8_f32(pv[2], pv[3], w0, true);
        int w1 = __builtin_amdgcn_cvt_pk_fp8_f32(pv[4], pv[5], 0, false);
        w1     = __builtin_amdgcn_cvt_pk_fp8_f32(pv[6], pv[7], w1, true);
        *(int2*)(ln8 + base + lane * 8) = make_int2(w0, w1);
    }
}

// ---------------- per-edge softmax numerators ----------------

__global__ __launch_bounds__(256) void k_edge(const int* __restrict__ csr_src,
                                              const int* __restrict__ csr_dst,
                                              const float* __restrict__ as_,
                                              const float* __restrict__ ad_,
                                              float* __restrict__ p) {
    int j = blockIdx.x * 256 + threadIdx.x;
    if (j >= E2) return;
    int s = csr_src[j];
    int d = csr_dst[j];
    float4 a4 = *(const float4*)(as_ + (size_t)s * 4);
    float4 b4 = *(const float4*)(ad_ + (size_t)d * 4);
    float4 r;
    float v;
    v = a4.x + b4.x; v = (v >= 0.f) ? v : NEG_SLOPE * v; r.x = __expf(v);
    v = a4.y + b4.y; v = (v >= 0.f) ? v : NEG_SLOPE * v; r.y = __expf(v);
    v = a4.z + b4.z; v = (v >= 0.f) ? v : NEG_SLOPE * v; r.z = __expf(v);
    v = a4.w + b4.w; v = (v >= 0.f) ? v : NEG_SLOPE * v; r.w = __expf(v);
    *(float4*)(p + (size_t)j * 4) = r;
}

// ---------------- per-node aggregate of fp8 LN rows; 1 wave per node; A-frag output ----------------
// agg frag layout: [tile][kc(16)][fraglane(64)][j(8)] fp16.
// Lane owns channels k = h*128 + lane*2 + {0,1}:
//   kc = h*4 + (lane>>4), fraglane = ((lane&15)>>2)*16 + (nd&15), j0 = 2*(lane&3).

__global__ __launch_bounds__(256) void k_agg(const unsigned char* __restrict__ ln8,
                                             const float* __restrict__ p,
                                             const int* __restrict__ row_ptr,
                                             const int* __restrict__ csr_src,
                                             _Float16* __restrict__ agg) {
    int tid = threadIdx.x;
    int lane = tid & 63;
    int nd = blockIdx.x * 4 + (tid >> 6);
    int e = row_ptr[nd], end = row_ptr[nd + 1];

    f32x2 ac0 = (f32x2)(0.f), ac1 = (f32x2)(0.f), ac2 = (f32x2)(0.f), ac3 = (f32x2)(0.f);
    float z0 = 0.f, z1 = 0.f, z2 = 0.f, z3 = 0.f;
    const unsigned char* xbase = ln8 + lane * 2;

    for (; e + 4 <= end; e += 4) {
        int src0 = csr_src[e], src1 = csr_src[e + 1], src2 = csr_src[e + 2], src3 = csr_src[e + 3];
        float4 p0 = *(const float4*)(p + (size_t)(e + 0) * 4);
        float4 p1 = *(const float4*)(p + (size_t)(e + 1) * 4);
        float4 p2 = *(const float4*)(p + (size_t)(e + 2) * 4);
        float4 p3 = *(const float4*)(p + (size_t)(e + 3) * 4);
        unsigned short w0 = *(const unsigned short*)(xbase + (size_t)src0 * 128);
        unsigned short w1 = *(const unsigned short*)(xbase + (size_t)src1 * 128);
        unsigned short w2 = *(const unsigned short*)(xbase + (size_t)src2 * 128);
        unsigned short w3 = *(const unsigned short*)(xbase + (size_t)src3 * 128);
        f32x2 v0 = __builtin_amdgcn_cvt_pk_f32_fp8((int)w0, false);
        f32x2 v1 = __builtin_amdgcn_cvt_pk_f32_fp8((int)w1, false);
        f32x2 v2 = __builtin_amdgcn_cvt_pk_f32_fp8((int)w2, false);
        f32x2 v3 = __builtin_amdgcn_cvt_pk_f32_fp8((int)w3, false);
        ac0 += (f32x2)(p0.x) * v0 + (f32x2)(p1.x) * v1 + (f32x2)(p2.x) * v2 + (f32x2)(p3.x) * v3;
        ac1 += (f32x2)(p0.y) * v0 + (f32x2)(p1.y) * v1 + (f32x2)(p2.y) * v2 + (f32x2)(p3.y) * v3;
        ac2 += (f32x2)(p0.z) * v0 + (f32x2)(p1.z) * v1 + (f32x2)(p2.z) * v2 + (f32x2)(p3.z) * v3;
        ac3 += (f32x2)(p0.w) * v0 + (f32x2)(p1.w) * v1 + (f32x2)(p2.w) * v2 + (f32x2)(p3.w) * v3;
        z0 += (p0.x + p1.x) + (p2.x + p3.x);
        z1 += (p0.y + p1.y) + (p2.y + p3.y);
        z2 += (p0.z + p1.z) + (p2.z + p3.z);
        z3 += (p0.w + p1.w) + (p2.w + p3.w);
    }
    for (; e < end; ++e) {
        int src0 = csr_src[e];
        float4 p0 = *(const float4*)(p + (size_t)e * 4);
        unsigned short w0 = *(const unsigned short*)(xbase + (size_t)src0 * 128);
        f32x2 v0 = __builtin_amdgcn_cvt_pk_f32_fp8((int)w0, false);
        ac0 += (f32x2)(p0.x) * v0;
        ac1 += (f32x2)(p0.y) * v0;
        ac2 += (f32x2)(p0.z) * v0;
        ac3 += (f32x2)(p0.w) * v0;
        z0 += p0.x; z1 += p0.y; z2 += p0.z; z3 += p0.w;
    }

    ac0 *= (f32x2)(1.0f / z0);
    ac1 *= (f32x2)(1.0f / z1);
    ac2 *= (f32x2)(1.0f / z2);
    ac3 *= (f32x2)(1.0f / z3);

    // frag-layout packed stores (4B = 2 fp16 per head)
    int tile = nd >> 4, m = nd & 15;
    int kcb  = lane >> 4;                     // kc = h*4 + kcb
    int fraglane = ((lane & 15) >> 2) * 16 + m;
    int j0 = 2 * (lane & 3);
    union { _Float16 hx[2]; unsigned int u; } cv;
    size_t tb = (size_t)tile * 16;
    cv.hx[0] = (_Float16)ac0[0]; cv.hx[1] = (_Float16)ac0[1];
    *(unsigned int*)(agg + ((tb + 0 * 4 + kcb) * 64 + fraglane) * 8 + j0) = cv.u;
    cv.hx[0] = (_Float16)ac1[0]; cv.hx[1] = (_Float16)ac1[1];
    *(unsigned int*)(agg + ((tb + 1 * 4 + kcb) * 64 + fraglane) * 8 + j0) = cv.u;
    cv.hx[0] = (_Float16)ac2[0]; cv.hx[1] = (_Float16)ac2[1];
    *(unsigned int*)(agg + ((tb + 2 * 4 + kcb) * 64 + fraglane) * 8 + j0) = cv.u;
    cv.hx[0] = (_Float16)ac3[0]; cv.hx[1] = (_Float16)ac3[1];
    *(unsigned int*)(agg + ((tb + 3 * 4 + kcb) * 64 + fraglane) * 8 + j0) = cv.u;
}

// ---------------- gemm2: agg(frag) x B''(LDS-staged) -> epilogue -> h, ln8, alphas ----------------
// 4 waves/block, one 16-row tile each; per-kc 8KB B slice staged in LDS and shared.

__global__ __launch_bounds__(256) void k_gemm2(const _Float16* __restrict__ agg,
                                               const _Float16* __restrict__ Bp,
                                               const float* __restrict__ ws,
                                               const float* __restrict__ bias,
                                               const float* __restrict__ gamma,
                                               const float* __restrict__ beta,
                                               float* __restrict__ h,
                                               unsigned char* __restrict__ ln8,
                                               float* __restrict__ as_,
                                               float* __restrict__ ad_,
                                               int write_ln) {
    __shared__ _Float16 Bs[4096];       // 8 KB: [nt(8)][lane(64)][j(8)]
    int tid = threadIdx.x;
    int lane = tid & 63;
    int w = tid >> 6;
    int tile = blockIdx.x * 4 + w;
    int valid = (tile < NT2);
    if (!valid) tile = 0;               // stay for barriers; all global writes guarded
    int quad = lane >> 4;
    int l15  = lane & 15;

    // staging indices: thread covers 16 fp16 (32 B) of the 8 KB slice
    int ntS  = tid >> 5;
    int remS = (tid & 31) * 16;

    f32x4 acc[8];
    for (int nt = 0; nt < 8; ++nt) acc[nt] = (f32x4)(0.0f);

    const _Float16* abase = agg + (size_t)tile * 8192 + lane * 8;
    for (int kc = 0; kc < 16; ++kc) {
        half8 a = *(const half8*)(abase + kc * 512);          // global, independent of LDS
        const _Float16* src = Bp + ((size_t)(ntS * 16 + kc)) * 512 + remS;
        __syncthreads();                                      // prior kc's reads done
        *(half8*)(Bs + tid * 16)     = *(const half8*)(src);
        *(half8*)(Bs + tid * 16 + 8) = *(const half8*)(src + 8);
        __syncthreads();                                      // slice visible
        for (int nt = 0; nt < 8; ++nt) {
            half8 b = *(const half8*)(Bs + nt * 512 + lane * 8);
            acc[nt] = __builtin_amdgcn_mfma_f32_16x16x32_f16(a, b, acc[nt], 0, 0, 0);
        }
    }

    if (!valid) return;                 // no barriers below

    int row0 = tile * 16;
    float bi[8];
    for (int nt = 0; nt < 8; ++nt) bi[nt] = bias[nt * 16 + l15];
    float ga[8], be[8], wsv[8][8];
    if (write_ln) {
        for (int nt = 0; nt < 8; ++nt) {
            int c = nt * 16 + l15;
            ga[nt] = gamma[c];
            be[nt] = beta[c];
            for (int j = 0; j < 8; ++j) wsv[nt][j] = ws[c * 8 + j];
        }
    }

    for (int r = 0; r < 4; ++r) {
        int node = row0 + quad * 4 + r;
        float* hr = h + (size_t)node * HID;
        float rv[8];
        for (int nt = 0; nt < 8; ++nt) {
            float t = acc[nt][r] + bi[nt];
            t = fmaxf(t, 0.f);
            rv[nt] = t + hr[nt * 16 + l15];
        }
        for (int nt = 0; nt < 8; ++nt) hr[nt * 16 + l15] = rv[nt];

        if (write_ln) {
            float s = 0.f;
            for (int nt = 0; nt < 8; ++nt) s += rv[nt];
            s += __shfl_xor(s, 1); s += __shfl_xor(s, 2);
            s += __shfl_xor(s, 4); s += __shfl_xor(s, 8);
            float mu = s * (1.0f / 128.0f);
            float var = 0.f;
            for (int nt = 0; nt < 8; ++nt) { float d = rv[nt] - mu; var += d * d; }
            var += __shfl_xor(var, 1); var += __shfl_xor(var, 2);
            var += __shfl_xor(var, 4); var += __shfl_xor(var, 8);
            float rstd = rsqrtf(var * (1.0f / 128.0f) + LN_EPS);
            float lnv[8];
            for (int nt = 0; nt < 8; ++nt)
                lnv[nt] = (rv[nt] - mu) * rstd * ga[nt] + be[nt];

            float ap[8];
            for (int j = 0; j < 8; ++j) {
                float t = 0.f;
                for (int nt = 0; nt < 8; ++nt) t += lnv[nt] * wsv[nt][j];
                ap[j] = t;
            }
            for (int j = 0; j < 8; ++j) {
                ap[j] += __shfl_xor(ap[j], 1); ap[j] += __shfl_xor(ap[j], 2);
                ap[j] += __shfl_xor(ap[j], 4); ap[j] += __shfl_xor(ap[j], 8);
            }
            if (l15 == 0) {
                for (int hh = 0; hh < 4; ++hh) {
                    as_[node * 4 + hh] = ap[hh];
                    ad_[node * 4 + hh] = ap[4 + hh];
                }
            }

            int w0 = __builtin_amdgcn_cvt_pk_fp8_f32(lnv[0], lnv[1], 0, false);
            w0     = __builtin_amdgcn_cvt_pk_fp8_f32(lnv[2], lnv[3], w0, true);
            int w1 = __builtin_amdgcn_cvt_pk_fp8_f32(lnv[4], lnv[5], 0, false);
            w1     = __builtin_amdgcn_cvt_pk_fp8_f32(lnv[6], lnv[7], w1, true);
            *(int2*)(ln8 + (size_t)node * 128 + l15 * 8) = make_int2(w0, w1);
        }
    }
}

// ---------------- output projection: LDS-staged W; 8 independent FMA chains per thread ----------------
// (2 nodes x 4 k-chunks) breaks the serial-accumulator latency cap seen in R16 (VALUBusy 28%).

__global__ __launch_bounds__(256) void k_out_proj(const float* __restrict__ h,
                                                  const float* __restrict__ W,
                                                  const float* __restrict__ b,
                                                  float* __restrict__ out) {
    __shared__ float Ws[HID * OUTC];
    int tid = threadIdx.x;
    for (int it = 0; it < 8; ++it) {
        int idx = (tid + it * 256) * 4;
        *(float4*)&Ws[idx] = *(const float4*)(W + idx);
    }
    __syncthreads();
    int j = tid & 63;
    int sub = tid >> 6;
    int nd0 = blockIdx.x * 8 + sub * 2;
    const float* h0 = h + (size_t)nd0 * HID;
    const float* h1 = h0 + HID;
    float a0[4] = {0.f, 0.f, 0.f, 0.f};
    float a1[4] = {0.f, 0.f, 0.f, 0.f};
    #pragma unroll 4
    for (int k = 0; k < 32; ++k) {
        #pragma unroll
        for (int c = 0; c < 4; ++c) {
            int kk = c * 32 + k;
            float w = Ws[kk * OUTC + j];
            a0[c] += h0[kk] * w;
            a1[c] += h1[kk] * w;
        }
    }
    float r0 = b[j] + (a0[0] + a0[1]) + (a0[2] + a0[3]);
    float r1 = b[j] + (a1[0] + a1[1]) + (a1[2] + a1[3]);
    out[(size_t)nd0 * OUTC + j]       = r0;
    out[(size_t)(nd0 + 1) * OUTC + j] = r1;
}

// ---------------- launch ----------------

extern "C" void kernel_launch(void* const* d_in, const int* in_sizes, int n_in,
                              void* d_out, int out_size, void* d_ws, size_t ws_size,
                              hipStream_t stream) {
    const float* x       = (const float*)d_in[0];
    const int*   ei      = (const int*)d_in[1];
    const float* W_in    = (const float*)d_in[2];
    const float* b_in    = (const float*)d_in[3];
    const float* W_conv  = (const float*)d_in[4];
    const float* att_src = (const float*)d_in[5];
    const float* att_dst = (const float*)d_in[6];
    const float* b_conv  = (const float*)d_in[7];
    const float* ln_g    = (const float*)d_in[8];
    const float* ln_b    = (const float*)d_in[9];
    const float* W_out   = (const float*)d_in[10];
    const float* b_out   = (const float*)d_in[11];
    float* out = (float*)d_out;

    char* ws = (char*)d_ws;
    size_t off = 0;
    auto alloc = [&](size_t bytes) { void* p = ws + off; off = (off + bytes + 255) & ~(size_t)255; return p; };
    float* h            = (float*)alloc((size_t)N_NODES * HID * 4);
    _Float16* agg       = (_Float16*)alloc((size_t)NT2 * 8192 * 2);   // frag layout
    unsigned char* ln8  = (unsigned char*)alloc((size_t)N_NODES * 128);
    float* as_          = (float*)alloc((size_t)N_NODES * 4 * 4);
    float* ad_          = (float*)alloc((size_t)N_NODES * 4 * 4);
    float* pedge        = (float*)alloc((size_t)E2 * HEADS * 4);
    _Float16* Bp2       = (_Float16*)alloc((size_t)DEPTH * 65536 * 2);
    float* ws_all       = (float*)alloc((size_t)DEPTH * 1024 * 4);
    int* deg    = (int*)alloc((size_t)N_NODES * 4);
    int* cur    = (int*)alloc((size_t)N_NODES * 4);
    int* row_ptr= (int*)alloc((size_t)(N_NODES + 1) * 4);
    int* csr    = (int*)alloc((size_t)E2 * 4);
    int* csrd   = (int*)alloc((size_t)E2 * 4);
    int* bsum   = (int*)alloc(256 * 4);
    (void)ws_size; (void)n_in; (void)in_sizes; (void)out_size;

    hipMemsetAsync(deg, 0, (size_t)N_NODES * 4, stream);
    hipMemsetAsync(cur, 0, (size_t)N_NODES * 4, stream);

    // CSR build
    k_deg<<<(E2 + 255) / 256, 256, 0, stream>>>(ei, deg);
    int nb = (N_NODES + 1023) / 1024;
    k_scan_block<<<nb, 1024, 0, stream>>>(deg, row_ptr, bsum, N_NODES);
    k_scan_bsum<<<1, 64, 0, stream>>>(bsum, nb);
    k_scan_fix<<<nb, 1024, 0, stream>>>(deg, row_ptr, bsum, N_NODES);
    k_fill<<<(E2 + 255) / 256, 256, 0, stream>>>(ei, row_ptr, cur, csr, csrd);

    // weight preprocessing (per call; graph-safe)
    k_ws<<<(DEPTH * 1024 + 255) / 256, 256, 0, stream>>>(W_conv, att_src, att_dst, ws_all);
    k_repackB2<<<(DEPTH * 65536 + 255) / 256, 256, 0, stream>>>(W_conv, Bp2);

    // input projection + first LN (fp8 table + layer-0 alphas)
    k_in_proj_ln<<<N_NODES / 4, 256, 0, stream>>>(x, W_in, b_in, ln_g, ln_b, ws_all,
                                                  h, ln8, as_, ad_);

    // layers
    for (int i = 0; i < DEPTH; ++i) {
        const float* bcp = b_conv + (size_t)i * HID;
        int write_ln = (i + 1 < DEPTH) ? 1 : 0;
        int nl = (i + 1 < DEPTH) ? i + 1 : i;
        const float* gp = ln_g + (size_t)nl * HID;
        const float* bp = ln_b + (size_t)nl * HID;
        const float* wsp = ws_all + (size_t)nl * 1024;

        k_edge<<<(E2 + 255) / 256, 256, 0, stream>>>(csr, csrd, as_, ad_, pedge);
        k_agg<<<N_NODES / 4, 256, 0, stream>>>(ln8, pedge, row_ptr, csr, agg);
        k_gemm2<<<(NT2 + 3) / 4, 256, 0, stream>>>(agg, Bp2 + (size_t)i * 65536, wsp,
                                                   bcp, gp, bp, h, ln8, as_, ad_, write_ln);
    }

    k_out_proj<<<N_NODES / 8, 256, 0, stream>>>(h, W_out, b_out, out);
}